// Round 18
// baseline (390.385 us; speedup 1.0000x reference)
//
#include <hip/hip_runtime.h>
#include <hip/hip_fp16.h>
#include <hip/hip_fp8.h>
#include <cstdint>

#define N_NODES 50000
#define M_PAD   50048
#define E_EDGES 800000
#define ETOT (E_EDGES + N_NODES)
#define G_GRAPHS 512
#define FIN 300
#define K1P 320
#define HC 256
#define NHID 300
#define NOUT 512
#define NBLK 196               // ceil(N_NODES / 256)
#define ROWB 391               // M_PAD / 128
#define QPX  49                // row-blocks per XCD (8*49 >= 391)
#define DRANGE 6250            // N_NODES / 8 dst-range per XCD
#define NCHUNK 128             // edge chunks per XCD-group
#define CHUNK_E ((ETOT + NCHUNK - 1) / NCHUNK)

typedef unsigned short u16;
typedef unsigned char  u8;
typedef __attribute__((ext_vector_type(8))) _Float16 f16x8;
typedef __attribute__((ext_vector_type(4))) float f32x4;
typedef __attribute__((ext_vector_type(2))) float f32x2;

__device__ __forceinline__ float leaky(float x){ return x > 0.f ? x : 0.2f * x; }

__device__ __forceinline__ int ntload_i(const int* p){
    return __builtin_nontemporal_load(p);
}
__device__ __forceinline__ float ntload_f(const float* p){
    return __builtin_nontemporal_load(p);
}

#if __has_builtin(__builtin_amdgcn_cvt_pk_fp8_f32) && __has_builtin(__builtin_amdgcn_cvt_pk_f32_fp8)
#define FP8_HW 1
#else
#define FP8_HW 0
#endif

#if __has_builtin(__builtin_amdgcn_global_load_lds)
#define ASYNC_LDS 1
#define GLDS(g, l) __builtin_amdgcn_global_load_lds( \
    (const __attribute__((address_space(1))) void*)(g), \
    (__attribute__((address_space(3))) void*)(l), 16, 0, 0)
#else
#define ASYNC_LDS 0
#endif

__device__ __forceinline__ u8 f2fp8(float v){
#if FP8_HW
    int b = __builtin_amdgcn_cvt_pk_fp8_f32(v, v, 0, false);
    return (u8)(b & 0xff);
#else
    return (u8)__hip_cvt_float_to_fp8(v, __HIP_SATFINITE, __HIP_E4M3);
#endif
}

// pack 8 f32 -> 8 fp8 bytes (two u32)
__device__ __forceinline__ uint2 f2fp8x8(const float* v){
#if FP8_HW
    int lo = 0, hi = 0;
    lo = __builtin_amdgcn_cvt_pk_fp8_f32(v[0], v[1], lo, false);
    lo = __builtin_amdgcn_cvt_pk_fp8_f32(v[2], v[3], lo, true);
    hi = __builtin_amdgcn_cvt_pk_fp8_f32(v[4], v[5], hi, false);
    hi = __builtin_amdgcn_cvt_pk_fp8_f32(v[6], v[7], hi, true);
    uint2 r; r.x = (unsigned)lo; r.y = (unsigned)hi; return r;
#else
    unsigned lo = 0, hi = 0;
    #pragma unroll
    for (int k = 0; k < 4; ++k) lo |= ((unsigned)f2fp8(v[k])) << (8 * k);
    #pragma unroll
    for (int k = 0; k < 4; ++k) hi |= ((unsigned)f2fp8(v[4 + k])) << (8 * k);
    uint2 r; r.x = lo; r.y = hi; return r;
#endif
}

// decode 4 packed fp8 (one u32) -> 4 floats
__device__ __forceinline__ f32x4 fp8x4tof(unsigned u){
#if FP8_HW
    f32x2 lo = __builtin_amdgcn_cvt_pk_f32_fp8(u, false);
    f32x2 hi = __builtin_amdgcn_cvt_pk_f32_fp8(u, true);
    return (f32x4){lo.x, lo.y, hi.x, hi.y};
#else
    auto d1 = [](u8 b)->float{
        __half_raw hr = __hip_cvt_fp8_to_halfraw((__hip_fp8_storage_t)b, __HIP_E4M3);
        return __half2float(*reinterpret_cast<__half*>(&hr));
    };
    return (f32x4){d1((u8)(u & 0xff)), d1((u8)((u >> 8) & 0xff)),
                   d1((u8)((u >> 16) & 0xff)), d1((u8)((u >> 24) & 0xff))};
#endif
}

__device__ __forceinline__ unsigned packh2(float a, float b){
    __half2 h = __floats2half2_rn(a, b);
    return *reinterpret_cast<unsigned*>(&h);
}
__device__ __forceinline__ float2 unpackh2(unsigned u){
    __half2 h = *reinterpret_cast<__half2*>(&u);
    return __half22float2(h);
}

__global__ void zero_i32(int* __restrict__ p, int n){
    int i = blockIdx.x * blockDim.x + threadIdx.x;
    if (i < n) p[i] = 0;
}

// XCD-partitioned histogram; non-temporal edge reads (don't evict counts lines)
__global__ __launch_bounds__(256) void hist_kernel(const int* __restrict__ ei,
                                                   int* __restrict__ counts){
    const int xcd = blockIdx.x & 7, chunk = blockIdx.x >> 3;
    const int lo = xcd * DRANGE, hi = lo + DRANGE;
    const int e0 = chunk * CHUNK_E;
    const int e1 = min(e0 + CHUNK_E, ETOT);
    for (int i = e0 + threadIdx.x; i < e1; i += 256){
        int d = (i < E_EDGES) ? ntload_i(ei + E_EDGES + i) : (i - E_EDGES);
        if (d >= lo && d < hi) atomicAdd(&counts[d], 1);
    }
}

// XCD-partitioned scatter; non-temporal edge reads (don't evict csr lines)
__global__ __launch_bounds__(256) void scatter_kernel(const int* __restrict__ ei,
                                                      int* __restrict__ cursor,
                                                      int* __restrict__ csr_src){
    const int xcd = blockIdx.x & 7, chunk = blockIdx.x >> 3;
    const int lo = xcd * DRANGE, hi = lo + DRANGE;
    const int e0 = chunk * CHUNK_E;
    const int e1 = min(e0 + CHUNK_E, ETOT);
    for (int i = e0 + threadIdx.x; i < e1; i += 256){
        int d = (i < E_EDGES) ? ntload_i(ei + E_EDGES + i) : (i - E_EDGES);
        if (d >= lo && d < hi){
            int s = (i < E_EDGES) ? ntload_i(ei + i) : (i - E_EDGES);
            int pos = atomicAdd(&cursor[d], 1);
            csr_src[pos] = s;
        }
    }
}

// ---- two-level scan ---------------------------------------------------------

__global__ __launch_bounds__(256) void bsum_kernel(const int* __restrict__ counts,
                                                   int* __restrict__ bsum){
    int b = blockIdx.x, t = threadIdx.x;
    int i = b * 256 + t;
    int v = (i < N_NODES) ? counts[i] : 0;
    #pragma unroll
    for (int o = 32; o >= 1; o >>= 1) v += __shfl_xor(v, o, 64);
    __shared__ int ws[4];
    if ((t & 63) == 0) ws[t >> 6] = v;
    __syncthreads();
    if (t == 0) bsum[b] = ws[0] + ws[1] + ws[2] + ws[3];
}

__global__ __launch_bounds__(256) void bscan_kernel(const int* __restrict__ bsum,
                                                    int* __restrict__ boff,
                                                    int* __restrict__ rs){
    int t = threadIdx.x;
    int v = (t < NBLK) ? bsum[t] : 0;
    __shared__ int sd[256];
    sd[t] = v;
    __syncthreads();
    for (int off = 1; off < 256; off <<= 1){
        int u = (t >= off) ? sd[t - off] : 0;
        __syncthreads();
        sd[t] += u;
        __syncthreads();
    }
    if (t < NBLK) boff[t] = sd[t] - v;     // exclusive
    if (t == 0) rs[N_NODES] = ETOT;
}

__global__ __launch_bounds__(256) void offsets_kernel(const int* __restrict__ counts,
                                                      const int* __restrict__ boff,
                                                      int* __restrict__ rs,
                                                      int* __restrict__ cursor){
    int b = blockIdx.x, t = threadIdx.x;
    int i = b * 256 + t;
    int v = (i < N_NODES) ? counts[i] : 0;
    __shared__ int sd[256];
    sd[t] = v;
    __syncthreads();
    for (int off = 1; off < 256; off <<= 1){
        int u = (t >= off) ? sd[t - off] : 0;
        __syncthreads();
        sd[t] += u;
        __syncthreads();
    }
    if (i < N_NODES){
        int o = boff[b] + sd[t] - v;
        rs[i] = o; cursor[i] = o;
    }
}

// ---- conversion kernels: fp32 -> fp16 ---------------------------------------

__global__ void conv_x_kernel(const float* __restrict__ x, __half* __restrict__ xf){
    int row = blockIdx.x, t = threadIdx.x;          // grid M_PAD, block 320
    float v = 0.f;
    if (row < N_NODES && t < FIN) v = ntload_f(x + (size_t)row * FIN + t);
    xf[(size_t)row * K1P + t] = __float2half(v);
}

__global__ void conv_w_kernel(const float* __restrict__ W, __half* __restrict__ wf,
                              int K, int Kp){
    int col = blockIdx.x, k = threadIdx.x;          // grid 256, block Kp
    float v = (k < K) ? W[(size_t)k * HC + col] : 0.f;
    wf[(size_t)col * Kp + k] = __float2half(v);
}

__global__ void pad_h_kernel(__half* __restrict__ hf){
    int row = N_NODES + blockIdx.x;                 // grid 48, block 256
    int t = threadIdx.x;
    hf[(size_t)row * HC + t] = __float2half(0.f);
}

// ---- fp16 MFMA GEMM, tile 128x128, fp8 output, async LDS staging ------------
// B cols permuted in LDS: LDS row p holds actual col 8*(p&15)+(p>>4), so lane
// fr's 8 outputs are consecutive cols 8*fr..8*fr+7 -> packed 8B epilogue store.
__global__ __launch_bounds__(256) void gemm_fp16(const __half* __restrict__ A,
                                                 const __half* __restrict__ Bt,
                                                 u8* __restrict__ Cq,
                                                 int Kp, int Mvalid){
    const int wgid = blockIdx.x;
    const int x    = wgid & 7, i = wgid >> 3;       // i in 0..97
    const int y    = x * QPX + (i >> 1);
    if (y >= ROWB) return;
    const int cx   = i & 1;
    const int col0 = cx * 128;
    const int row0 = y * 128;

    __shared__ u16 smem[16384];                     // 32 KB
    char* sb = (char*)smem;
    const int t    = threadIdx.x;
    const int lane = t & 63;
    const int w    = t >> 6;                        // wave 0..3 -> rows w*32..
    const int fr   = lane & 15, fq = lane >> 4;

    const int rA0 = t >> 2, sA0 = t & 3;            // LDS rows 0..63 (+64)
    const int ss0 = sA0 ^ ((rA0 >> 1) & 3);         // pre-swizzled source slot
    const int ss1 = sA0 ^ (((rA0 + 64) >> 1) & 3);
    const int wb  = (t & ~63) * 16;                 // wave-uniform byte base

    // B-col permutation: LDS row p <- global B row col0 + 8*(p&15) + (p>>4)
    const int bp0 = 8 * (rA0 & 15) + (rA0 >> 4);
    const int bp1 = 8 * ((rA0 + 64) & 15) + ((rA0 + 64) >> 4);

    auto aoff = [](int db, int row, int slot)->int{ // u16-element offset (reads)
        return db * 4096 + row * 32 + ((slot ^ ((row >> 1) & 3)) * 8);
    };
    auto boff = [](int db, int row, int slot)->int{
        return 8192 + db * 4096 + row * 32 + ((slot ^ ((row >> 1) & 3)) * 8);
    };

    f32x4 acc[2][8];
    #pragma unroll
    for (int m = 0; m < 2; ++m)
        #pragma unroll
        for (int n = 0; n < 8; ++n) acc[m][n] = (f32x4){0.f, 0.f, 0.f, 0.f};

    const int nt = Kp >> 5;

#if ASYNC_LDS
    auto stage = [&](int kt, int db){
        const int k0 = kt * 32;
        GLDS(A  + (size_t)(row0 + rA0)      * Kp + k0 + ss0 * 8, sb + db*8192 + wb);
        GLDS(A  + (size_t)(row0 + rA0 + 64) * Kp + k0 + ss1 * 8, sb + db*8192 + 4096 + wb);
        GLDS(Bt + (size_t)(col0 + bp0)      * Kp + k0 + ss0 * 8, sb + 16384 + db*8192 + wb);
        GLDS(Bt + (size_t)(col0 + bp1)      * Kp + k0 + ss1 * 8, sb + 16384 + db*8192 + 4096 + wb);
    };
    stage(0, 0);
    __syncthreads();
#else
    int4 va0, va1, vb0, vb1;
    auto stage_load = [&](int kt){
        const int k0 = kt * 32;
        va0 = *(const int4*)(A  + (size_t)(row0 + rA0)      * Kp + k0 + ss0 * 8);
        va1 = *(const int4*)(A  + (size_t)(row0 + rA0 + 64) * Kp + k0 + ss1 * 8);
        vb0 = *(const int4*)(Bt + (size_t)(col0 + bp0)      * Kp + k0 + ss0 * 8);
        vb1 = *(const int4*)(Bt + (size_t)(col0 + bp1)      * Kp + k0 + ss1 * 8);
    };
    auto stage_write = [&](int db){
        *(int4*)(sb + db*8192 + (rA0)*64 + sA0*16)            = va0;
        *(int4*)(sb + db*8192 + 4096 + (rA0)*64 + sA0*16)     = va1;
        *(int4*)(sb + 16384 + db*8192 + (rA0)*64 + sA0*16)    = vb0;
        *(int4*)(sb + 16384 + db*8192 + 4096 + (rA0)*64 + sA0*16) = vb1;
    };
    stage_load(0); stage_write(0);
    __syncthreads();
#endif

    for (int kt = 0; kt < nt; ++kt){
        const int db = kt & 1;
#if ASYNC_LDS
        if (kt + 1 < nt) stage(kt + 1, db ^ 1);     // async into other buffer
#else
        if (kt + 1 < nt) stage_load(kt + 1);
#endif

        f16x8 af[2], bf[8];
        #pragma unroll
        for (int m = 0; m < 2; ++m){
            int row = w * 32 + m * 16 + fr;
            af[m] = *(const f16x8*)&smem[aoff(db, row, fq)];
        }
        #pragma unroll
        for (int n = 0; n < 8; ++n){
            int col = n * 16 + fr;                  // LDS row (permuted)
            bf[n] = *(const f16x8*)&smem[boff(db, col, fq)];
        }
        #pragma unroll
        for (int m = 0; m < 2; ++m)
            #pragma unroll
            for (int n = 0; n < 8; ++n)
                acc[m][n] = __builtin_amdgcn_mfma_f32_16x16x32_f16(af[m], bf[n], acc[m][n], 0, 0, 0);

#if !ASYNC_LDS
        if (kt + 1 < nt) stage_write(db ^ 1);
#endif
        __syncthreads();
    }

    // lane fr owns actual cols 8*fr..8*fr+7 (acc[m][n][r] -> col 8*fr+n)
    #pragma unroll
    for (int m = 0; m < 2; ++m){
        int rowb = row0 + w * 32 + m * 16 + fq * 4;
        #pragma unroll
        for (int r = 0; r < 4; ++r){
            int row = rowb + r;
            if (row < Mvalid){
                float v8[8];
                #pragma unroll
                for (int n = 0; n < 8; ++n) v8[n] = acc[m][n][r];
                uint2 pk = f2fp8x8(v8);
                *(uint2*)(Cq + (size_t)row * HC + col0 + 8 * fr) = pk;
            }
        }
    }
}

// per-node attention logits from fp8 htq (lane -> cols 4l..4l+3)
__global__ __launch_bounds__(256) void al_kernel(const u8* __restrict__ htq,
                                                 const float* __restrict__ a_s,
                                                 const float* __restrict__ a_d,
                                                 float* __restrict__ als,
                                                 float* __restrict__ ald){
    int wave = threadIdx.x >> 6, lane = threadIdx.x & 63;
    int n = blockIdx.x * 4 + wave;
    if (n >= N_NODES) return;
    const unsigned u = *(const unsigned*)(htq + (size_t)n * HC + 4 * lane);
    f32x4 f = fp8x4tof(u);
    const float4 as4 = *(const float4*)(a_s + 4 * lane);
    const float4 ad4 = *(const float4*)(a_d + 4 * lane);
    float ps = f.x * as4.x + f.y * as4.y + f.z * as4.z + f.w * as4.w;
    float pd = f.x * ad4.x + f.y * ad4.y + f.z * ad4.z + f.w * ad4.w;
    #pragma unroll
    for (int o = 8; o >= 1; o >>= 1){
        ps += __shfl_xor(ps, o, 64);
        pd += __shfl_xor(pd, o, 64);
    }
    if ((lane & 15) == 0){
        als[n * 4 + (lane >> 4)] = ps;
        ald[n * 4 + (lane >> 4)] = pd;
    }
}

// one wave per destination node: no-max softmax + fp8 gather, 8-deep chunks,
// 2 shuffles/edge.
__global__ __launch_bounds__(256) void aggregate_kernel(const u8* __restrict__ htq,
                                                        const float* __restrict__ als,
                                                        const float* __restrict__ ald,
                                                        const int* __restrict__ rs,
                                                        const int* __restrict__ csr,
                                                        const float* __restrict__ bias,
                                                        __half* __restrict__ hf,
                                                        int do_relu){
    int wave = threadIdx.x >> 6, lane = threadIdx.x & 63;
    int n = blockIdx.x * 4 + wave;
    if (n >= N_NODES) return;
    const int s0 = rs[n], s1 = rs[n + 1];
    const int deg = s1 - s0;
    const int hsel = lane >> 4;             // head owning cols 4l..4l+3
    const float4 adv = *(const float4*)(ald + (size_t)n * 4);
    const float ad0 = adv.x, ad1 = adv.y, ad2 = adv.z, ad3 = adv.w;

    float4 acc = {0.f, 0.f, 0.f, 0.f};
    float sm0 = 0.f, sm1 = 0.f, sm2 = 0.f, sm3 = 0.f;

    if (deg <= 64){
        const int i = s0 + lane;
        int s = 0;
        float ex0 = 0.f, ex1 = 0.f, ex2 = 0.f, ex3 = 0.f;
        if (i < s1){
            s = csr[i];
            float4 a = *(const float4*)(als + (size_t)s * 4);
            ex0 = __expf(leaky(a.x + ad0));
            ex1 = __expf(leaky(a.y + ad1));
            ex2 = __expf(leaky(a.z + ad2));
            ex3 = __expf(leaky(a.w + ad3));
        }
        sm0 = ex0; sm1 = ex1; sm2 = ex2; sm3 = ex3;
        const unsigned psel = (hsel < 2) ? packh2(ex0, ex1) : packh2(ex2, ex3);
        const bool evH = ((hsel & 1) == 0);

        const int dp = (deg + 7) & ~7;
        for (int j = 0; j < dp; j += 8){
            int sj[8]; float aw[8];
            #pragma unroll
            for (int k = 0; k < 8; ++k){
                const int jj = j + k;
                sj[k] = __shfl(s, jj, 64);
                unsigned q = __shfl(psel, jj, 64);
                float2 f2 = unpackh2(q);
                aw[k] = evH ? f2.x : f2.y;
            }
            unsigned u[8];
            #pragma unroll
            for (int k = 0; k < 8; ++k)
                u[k] = *(const unsigned*)(htq + (size_t)sj[k] * HC + 4 * lane);
            #pragma unroll
            for (int k = 0; k < 8; ++k){
                f32x4 f = fp8x4tof(u[k]);
                acc.x += aw[k] * f.x; acc.y += aw[k] * f.y;
                acc.z += aw[k] * f.z; acc.w += aw[k] * f.w;
            }
        }
    } else {
        // slow path (deg > 64): rare, correctness only
        for (int base = s0; base < s1; base += 64){
            const int i = base + lane;
            int s = 0;
            float ex0 = 0.f, ex1 = 0.f, ex2 = 0.f, ex3 = 0.f;
            if (i < s1){
                s = csr[i];
                float4 a = *(const float4*)(als + (size_t)s * 4);
                ex0 = __expf(leaky(a.x + ad0));
                ex1 = __expf(leaky(a.y + ad1));
                ex2 = __expf(leaky(a.z + ad2));
                ex3 = __expf(leaky(a.w + ad3));
            }
            sm0 += ex0; sm1 += ex1; sm2 += ex2; sm3 += ex3;
            const int cnt = min(64, s1 - base);
            for (int j = 0; j < cnt; ++j){
                int   sj = __shfl(s,   j, 64);
                float a0 = __shfl(ex0, j, 64);
                float a1 = __shfl(ex1, j, 64);
                float a2 = __shfl(ex2, j, 64);
                float a3 = __shfl(ex3, j, 64);
                float x0 = (hsel == 0) ? a0 : a1;
                float x1 = (hsel == 2) ? a2 : a3;
                float aw = (hsel < 2) ? x0 : x1;
                unsigned u = *(const unsigned*)(htq + (size_t)sj * HC + 4 * lane);
                f32x4 f = fp8x4tof(u);
                acc.x += aw * f.x; acc.y += aw * f.y;
                acc.z += aw * f.z; acc.w += aw * f.w;
            }
        }
    }

    #pragma unroll
    for (int o = 32; o >= 1; o >>= 1){
        sm0 += __shfl_xor(sm0, o, 64);
        sm1 += __shfl_xor(sm1, o, 64);
        sm2 += __shfl_xor(sm2, o, 64);
        sm3 += __shfl_xor(sm3, o, 64);
    }
    float x0 = (hsel == 0) ? sm0 : sm1;
    float x1 = (hsel == 2) ? sm2 : sm3;
    const float inv = 1.f / (((hsel < 2) ? x0 : x1) + 1e-16f);

    const float4 bv = *(const float4*)(bias + 4 * lane);
    float v0 = acc.x * inv + bv.x;
    float v1 = acc.y * inv + bv.y;
    float v2 = acc.z * inv + bv.z;
    float v3 = acc.w * inv + bv.w;
    if (do_relu){
        v0 = fmaxf(v0, 0.f); v1 = fmaxf(v1, 0.f);
        v2 = fmaxf(v2, 0.f); v3 = fmaxf(v3, 0.f);
    }
    ushort4 p;
    p.x = __half_as_ushort(__float2half(v0));
    p.y = __half_as_ushort(__float2half(v1));
    p.z = __half_as_ushort(__float2half(v2));
    p.w = __half_as_ushort(__float2half(v3));
    *(ushort4*)((u16*)hf + (size_t)n * HC + 4 * lane) = p;
}

__global__ void gstart_kernel(const int* __restrict__ batch, int* __restrict__ gstart){
    int g = blockIdx.x * blockDim.x + threadIdx.x;
    if (g > G_GRAPHS) return;
    int lo = 0, hi = N_NODES;
    while (lo < hi){
        int mid = (lo + hi) >> 1;
        if (batch[mid] < g) lo = mid + 1; else hi = mid;
    }
    gstart[g] = lo;
}

__global__ __launch_bounds__(256) void pool_kernel(const __half* __restrict__ h,
                                                   const int* __restrict__ gstart,
                                                   float* __restrict__ pooled){
    int g = blockIdx.x, t = threadIdx.x;
    int s0 = gstart[g], s1 = gstart[g + 1];
    float sum = 0.f;
    for (int n = s0; n < s1; ++n) sum += __half2float(h[(size_t)n * HC + t]);
    pooled[g * HC + t] = sum / fmaxf((float)(s1 - s0), 1.f);
}

__global__ void mlp1_kernel(const float* __restrict__ pooled, const float* __restrict__ Wm1,
                            const float* __restrict__ bm1, float* __restrict__ z){
    int g = blockIdx.x, j = threadIdx.x;
    if (j >= NHID) return;
    float acc = bm1[j];
    for (int k = 0; k < HC; ++k) acc += pooled[g * HC + k] * Wm1[(size_t)k * NHID + j];
    z[g * NHID + j] = fmaxf(acc, 0.f);
}

__global__ void mlp2_kernel(const float* __restrict__ z, const float* __restrict__ Wm2,
                            const float* __restrict__ bm2, float* __restrict__ out){
    int g = blockIdx.x, j = threadIdx.x;
    float acc = bm2[j];
    for (int k = 0; k < NHID; ++k) acc += z[g * NHID + k] * Wm2[(size_t)k * NOUT + j];
    out[g * NOUT + j] = acc;
}

extern "C" void kernel_launch(void* const* d_in, const int* in_sizes, int n_in,
                              void* d_out, int out_size, void* d_ws, size_t ws_size,
                              hipStream_t stream){
    const float* x    = (const float*)d_in[0];
    const int*   ei   = (const int*)  d_in[1];
    const int*   batch= (const int*)  d_in[2];
    const float* W1   = (const float*)d_in[3];
    const float* a1s  = (const float*)d_in[4];
    const float* a1d  = (const float*)d_in[5];
    const float* b1   = (const float*)d_in[6];
    const float* W2   = (const float*)d_in[7];
    const float* a2s  = (const float*)d_in[8];
    const float* a2d  = (const float*)d_in[9];
    const float* b2   = (const float*)d_in[10];
    const float* W3   = (const float*)d_in[11];
    const float* a3s  = (const float*)d_in[12];
    const float* a3d  = (const float*)d_in[13];
    const float* b3   = (const float*)d_in[14];
    const float* Wm1  = (const float*)d_in[15];
    const float* bm1  = (const float*)d_in[16];
    const float* Wm2  = (const float*)d_in[17];
    const float* bm2  = (const float*)d_in[18];
    float* out = (float*)d_out;

    char* ws = (char*)d_ws;
    size_t off = 0;
    auto alloc = [&](size_t bytes)->char*{
        char* p = ws + off;
        off = (off + bytes + 255) & ~(size_t)255;
        return p;
    };
    __half* xf    = (__half*)alloc((size_t)M_PAD * K1P * 2);    // reused as layer-3 out
    __half* hf    = (__half*)alloc((size_t)M_PAD * HC * 2);
    u8*     htq   = (u8*)   alloc((size_t)N_NODES * HC);
    __half* hout  = xf;                                         // layer-3 output (xf dead)
    __half* wt1   = (__half*)alloc((size_t)HC * K1P * 2);
    __half* wt2   = (__half*)alloc((size_t)HC * HC * 2);
    __half* wt3   = (__half*)alloc((size_t)HC * HC * 2);
    float* als    = (float*)alloc((size_t)N_NODES * 4 * 4);
    float* ald    = (float*)alloc((size_t)N_NODES * 4 * 4);
    int*   counts = (int*)  alloc((size_t)N_NODES * 4);
    int*   rs     = (int*)  alloc((size_t)(N_NODES + 1) * 4);
    int*   cursor = (int*)  alloc((size_t)N_NODES * 4);
    int*   csr    = (int*)  alloc((size_t)ETOT * 4);
    int*   bsum   = (int*)  alloc(256 * 4);
    int*   boffs  = (int*)  alloc(256 * 4);
    int*   gstart = (int*)  alloc((size_t)(G_GRAPHS + 1) * 4);
    float* pooled = (float*)alloc((size_t)G_GRAPHS * HC * 4);
    float* zbuf   = (float*)alloc((size_t)G_GRAPHS * NHID * 4);

    conv_x_kernel<<<M_PAD, K1P, 0, stream>>>(x, xf);
    conv_w_kernel<<<HC, K1P, 0, stream>>>(W1, wt1, FIN, K1P);
    conv_w_kernel<<<HC, HC, 0, stream>>>(W2, wt2, HC, HC);
    conv_w_kernel<<<HC, HC, 0, stream>>>(W3, wt3, HC, HC);
    pad_h_kernel<<<M_PAD - N_NODES, HC, 0, stream>>>(hf);

    zero_i32<<<(N_NODES + 255) / 256, 256, 0, stream>>>(counts, N_NODES);
    hist_kernel<<<8 * NCHUNK, 256, 0, stream>>>(ei, counts);
    bsum_kernel<<<NBLK, 256, 0, stream>>>(counts, bsum);
    bscan_kernel<<<1, 256, 0, stream>>>(bsum, boffs, rs);
    offsets_kernel<<<NBLK, 256, 0, stream>>>(counts, boffs, rs, cursor);
    scatter_kernel<<<8 * NCHUNK, 256, 0, stream>>>(ei, cursor, csr);
    gstart_kernel<<<3, 256, 0, stream>>>(batch, gstart);

    const int GG = 8 * 98;                 // 784 blocks, XCD row-pair mapping

    // layer 1
    gemm_fp16<<<GG, 256, 0, stream>>>(xf, wt1, htq, K1P, N_NODES);
    al_kernel<<<(N_NODES + 3) / 4, 256, 0, stream>>>(htq, a1s, a1d, als, ald);
    aggregate_kernel<<<(N_NODES + 3) / 4, 256, 0, stream>>>(htq, als, ald, rs, csr,
                                                            b1, hf, 1);
    // layer 2
    gemm_fp16<<<GG, 256, 0, stream>>>(hf, wt2, htq, HC, N_NODES);
    al_kernel<<<(N_NODES + 3) / 4, 256, 0, stream>>>(htq, a2s, a2d, als, ald);
    aggregate_kernel<<<(N_NODES + 3) / 4, 256, 0, stream>>>(htq, als, ald, rs, csr,
                                                            b2, hf, 1);
    // layer 3 (output into hout = xf)
    gemm_fp16<<<GG, 256, 0, stream>>>(hf, wt3, htq, HC, N_NODES);
    al_kernel<<<(N_NODES + 3) / 4, 256, 0, stream>>>(htq, a3s, a3d, als, ald);
    aggregate_kernel<<<(N_NODES + 3) / 4, 256, 0, stream>>>(htq, als, ald, rs, csr,
                                                            b3, hout, 0);

    pool_kernel<<<G_GRAPHS, 256, 0, stream>>>(hout, gstart, pooled);
    mlp1_kernel<<<G_GRAPHS, 320, 0, stream>>>(pooled, Wm1, bm1, zbuf);
    mlp2_kernel<<<G_GRAPHS, 512, 0, stream>>>(zbuf, Wm2, bm2, out);
}

// Round 19
// 374.141 us; speedup vs baseline: 1.0434x; 1.0434x over previous
//
#include <hip/hip_runtime.h>
#include <hip/hip_fp16.h>
#include <hip/hip_fp8.h>
#include <cstdint>

#define N_NODES 50000
#define M_PAD   50048
#define E_EDGES 800000
#define ETOT (E_EDGES + N_NODES)
#define G_GRAPHS 512
#define FIN 300
#define K1P 320
#define HC 256
#define NHID 300
#define NOUT 512
#define NBLK 196               // ceil(N_NODES / 256)
#define ROWB 391               // M_PAD / 128
#define QPX  49                // row-blocks per XCD (8*49 >= 391)
#define DRANGE 6250            // N_NODES / 8 dst-range per XCD
#define NCHUNK 128             // edge chunks per XCD-group
#define CHUNK_E ((ETOT + NCHUNK - 1) / NCHUNK)

typedef unsigned short u16;
typedef unsigned char  u8;
typedef __attribute__((ext_vector_type(8))) _Float16 f16x8;
typedef __attribute__((ext_vector_type(4))) float f32x4;
typedef __attribute__((ext_vector_type(2))) float f32x2;

__device__ __forceinline__ float leaky(float x){ return x > 0.f ? x : 0.2f * x; }

#if __has_builtin(__builtin_amdgcn_cvt_pk_fp8_f32) && __has_builtin(__builtin_amdgcn_cvt_pk_f32_fp8)
#define FP8_HW 1
#else
#define FP8_HW 0
#endif

#if __has_builtin(__builtin_amdgcn_global_load_lds)
#define ASYNC_LDS 1
#define GLDS(g, l) __builtin_amdgcn_global_load_lds( \
    (const __attribute__((address_space(1))) void*)(g), \
    (__attribute__((address_space(3))) void*)(l), 16, 0, 0)
#else
#define ASYNC_LDS 0
#endif

__device__ __forceinline__ u8 f2fp8(float v){
#if FP8_HW
    int b = __builtin_amdgcn_cvt_pk_fp8_f32(v, v, 0, false);
    return (u8)(b & 0xff);
#else
    return (u8)__hip_cvt_float_to_fp8(v, __HIP_SATFINITE, __HIP_E4M3);
#endif
}

// pack 8 f32 -> 8 fp8 bytes (two u32)
__device__ __forceinline__ uint2 f2fp8x8(const float* v){
#if FP8_HW
    int lo = 0, hi = 0;
    lo = __builtin_amdgcn_cvt_pk_fp8_f32(v[0], v[1], lo, false);
    lo = __builtin_amdgcn_cvt_pk_fp8_f32(v[2], v[3], lo, true);
    hi = __builtin_amdgcn_cvt_pk_fp8_f32(v[4], v[5], hi, false);
    hi = __builtin_amdgcn_cvt_pk_fp8_f32(v[6], v[7], hi, true);
    uint2 r; r.x = (unsigned)lo; r.y = (unsigned)hi; return r;
#else
    unsigned lo = 0, hi = 0;
    #pragma unroll
    for (int k = 0; k < 4; ++k) lo |= ((unsigned)f2fp8(v[k])) << (8 * k);
    #pragma unroll
    for (int k = 0; k < 4; ++k) hi |= ((unsigned)f2fp8(v[4 + k])) << (8 * k);
    uint2 r; r.x = lo; r.y = hi; return r;
#endif
}

// decode 4 packed fp8 (one u32) -> 4 floats
__device__ __forceinline__ f32x4 fp8x4tof(unsigned u){
#if FP8_HW
    f32x2 lo = __builtin_amdgcn_cvt_pk_f32_fp8(u, false);
    f32x2 hi = __builtin_amdgcn_cvt_pk_f32_fp8(u, true);
    return (f32x4){lo.x, lo.y, hi.x, hi.y};
#else
    auto d1 = [](u8 b)->float{
        __half_raw hr = __hip_cvt_fp8_to_halfraw((__hip_fp8_storage_t)b, __HIP_E4M3);
        return __half2float(*reinterpret_cast<__half*>(&hr));
    };
    return (f32x4){d1((u8)(u & 0xff)), d1((u8)((u >> 8) & 0xff)),
                   d1((u8)((u >> 16) & 0xff)), d1((u8)((u >> 24) & 0xff))};
#endif
}

__device__ __forceinline__ unsigned packh2(float a, float b){
    __half2 h = __floats2half2_rn(a, b);
    return *reinterpret_cast<unsigned*>(&h);
}
__device__ __forceinline__ float2 unpackh2(unsigned u){
    __half2 h = *reinterpret_cast<__half2*>(&u);
    return __half22float2(h);
}

__global__ void zero_i32(int* __restrict__ p, int n){
    int i = blockIdx.x * blockDim.x + threadIdx.x;
    if (i < n) p[i] = 0;
}

// XCD-partitioned histogram
__global__ __launch_bounds__(256) void hist_kernel(const int* __restrict__ ei,
                                                   int* __restrict__ counts){
    const int xcd = blockIdx.x & 7, chunk = blockIdx.x >> 3;
    const int lo = xcd * DRANGE, hi = lo + DRANGE;
    const int e0 = chunk * CHUNK_E;
    const int e1 = min(e0 + CHUNK_E, ETOT);
    for (int i = e0 + threadIdx.x; i < e1; i += 256){
        int d = (i < E_EDGES) ? ei[E_EDGES + i] : (i - E_EDGES);
        if (d >= lo && d < hi) atomicAdd(&counts[d], 1);
    }
}

// XCD-partitioned scatter
__global__ __launch_bounds__(256) void scatter_kernel(const int* __restrict__ ei,
                                                      int* __restrict__ cursor,
                                                      int* __restrict__ csr_src){
    const int xcd = blockIdx.x & 7, chunk = blockIdx.x >> 3;
    const int lo = xcd * DRANGE, hi = lo + DRANGE;
    const int e0 = chunk * CHUNK_E;
    const int e1 = min(e0 + CHUNK_E, ETOT);
    for (int i = e0 + threadIdx.x; i < e1; i += 256){
        int d = (i < E_EDGES) ? ei[E_EDGES + i] : (i - E_EDGES);
        if (d >= lo && d < hi){
            int s = (i < E_EDGES) ? ei[i] : (i - E_EDGES);
            int pos = atomicAdd(&cursor[d], 1);
            csr_src[pos] = s;
        }
    }
}

// ---- two-level scan ---------------------------------------------------------

__global__ __launch_bounds__(256) void bsum_kernel(const int* __restrict__ counts,
                                                   int* __restrict__ bsum){
    int b = blockIdx.x, t = threadIdx.x;
    int i = b * 256 + t;
    int v = (i < N_NODES) ? counts[i] : 0;
    #pragma unroll
    for (int o = 32; o >= 1; o >>= 1) v += __shfl_xor(v, o, 64);
    __shared__ int ws[4];
    if ((t & 63) == 0) ws[t >> 6] = v;
    __syncthreads();
    if (t == 0) bsum[b] = ws[0] + ws[1] + ws[2] + ws[3];
}

__global__ __launch_bounds__(256) void bscan_kernel(const int* __restrict__ bsum,
                                                    int* __restrict__ boff,
                                                    int* __restrict__ rs){
    int t = threadIdx.x;
    int v = (t < NBLK) ? bsum[t] : 0;
    __shared__ int sd[256];
    sd[t] = v;
    __syncthreads();
    for (int off = 1; off < 256; off <<= 1){
        int u = (t >= off) ? sd[t - off] : 0;
        __syncthreads();
        sd[t] += u;
        __syncthreads();
    }
    if (t < NBLK) boff[t] = sd[t] - v;     // exclusive
    if (t == 0) rs[N_NODES] = ETOT;
}

__global__ __launch_bounds__(256) void offsets_kernel(const int* __restrict__ counts,
                                                      const int* __restrict__ boff,
                                                      int* __restrict__ rs,
                                                      int* __restrict__ cursor){
    int b = blockIdx.x, t = threadIdx.x;
    int i = b * 256 + t;
    int v = (i < N_NODES) ? counts[i] : 0;
    __shared__ int sd[256];
    sd[t] = v;
    __syncthreads();
    for (int off = 1; off < 256; off <<= 1){
        int u = (t >= off) ? sd[t - off] : 0;
        __syncthreads();
        sd[t] += u;
        __syncthreads();
    }
    if (i < N_NODES){
        int o = boff[b] + sd[t] - v;
        rs[i] = o; cursor[i] = o;
    }
}

// ---- conversion kernels: fp32 -> fp16 ---------------------------------------

__global__ void conv_x_kernel(const float* __restrict__ x, __half* __restrict__ xf){
    int row = blockIdx.x, t = threadIdx.x;          // grid M_PAD, block 320
    float v = 0.f;
    if (row < N_NODES && t < FIN) v = x[(size_t)row * FIN + t];
    xf[(size_t)row * K1P + t] = __float2half(v);
}

__global__ void conv_w_kernel(const float* __restrict__ W, __half* __restrict__ wf,
                              int K, int Kp){
    int col = blockIdx.x, k = threadIdx.x;          // grid 256, block Kp
    float v = (k < K) ? W[(size_t)k * HC + col] : 0.f;
    wf[(size_t)col * Kp + k] = __float2half(v);
}

__global__ void pad_h_kernel(__half* __restrict__ hf){
    int row = N_NODES + blockIdx.x;                 // grid 48, block 256
    int t = threadIdx.x;
    hf[(size_t)row * HC + t] = __float2half(0.f);
}

// ---- fp16 MFMA GEMM, tile 128x128, fp8 output, async LDS staging ------------
// B cols permuted in LDS: LDS row p holds actual col 8*(p&15)+(p>>4), so lane
// fr's 8 outputs are consecutive cols 8*fr..8*fr+7 -> packed 8B epilogue store.
__global__ __launch_bounds__(256) void gemm_fp16(const __half* __restrict__ A,
                                                 const __half* __restrict__ Bt,
                                                 u8* __restrict__ Cq,
                                                 int Kp, int Mvalid){
    const int wgid = blockIdx.x;
    const int x    = wgid & 7, i = wgid >> 3;       // i in 0..97
    const int y    = x * QPX + (i >> 1);
    if (y >= ROWB) return;
    const int cx   = i & 1;
    const int col0 = cx * 128;
    const int row0 = y * 128;

    __shared__ u16 smem[16384];                     // 32 KB
    char* sb = (char*)smem;
    const int t    = threadIdx.x;
    const int lane = t & 63;
    const int w    = t >> 6;                        // wave 0..3 -> rows w*32..
    const int fr   = lane & 15, fq = lane >> 4;

    const int rA0 = t >> 2, sA0 = t & 3;            // LDS rows 0..63 (+64)
    const int ss0 = sA0 ^ ((rA0 >> 1) & 3);         // pre-swizzled source slot
    const int ss1 = sA0 ^ (((rA0 + 64) >> 1) & 3);
    const int wb  = (t & ~63) * 16;                 // wave-uniform byte base

    // B-col permutation: LDS row p <- global B row col0 + 8*(p&15) + (p>>4)
    const int bp0 = 8 * (rA0 & 15) + (rA0 >> 4);
    const int bp1 = 8 * ((rA0 + 64) & 15) + ((rA0 + 64) >> 4);

    auto aoff = [](int db, int row, int slot)->int{ // u16-element offset (reads)
        return db * 4096 + row * 32 + ((slot ^ ((row >> 1) & 3)) * 8);
    };
    auto boff = [](int db, int row, int slot)->int{
        return 8192 + db * 4096 + row * 32 + ((slot ^ ((row >> 1) & 3)) * 8);
    };

    f32x4 acc[2][8];
    #pragma unroll
    for (int m = 0; m < 2; ++m)
        #pragma unroll
        for (int n = 0; n < 8; ++n) acc[m][n] = (f32x4){0.f, 0.f, 0.f, 0.f};

    const int nt = Kp >> 5;

#if ASYNC_LDS
    auto stage = [&](int kt, int db){
        const int k0 = kt * 32;
        GLDS(A  + (size_t)(row0 + rA0)      * Kp + k0 + ss0 * 8, sb + db*8192 + wb);
        GLDS(A  + (size_t)(row0 + rA0 + 64) * Kp + k0 + ss1 * 8, sb + db*8192 + 4096 + wb);
        GLDS(Bt + (size_t)(col0 + bp0)      * Kp + k0 + ss0 * 8, sb + 16384 + db*8192 + wb);
        GLDS(Bt + (size_t)(col0 + bp1)      * Kp + k0 + ss1 * 8, sb + 16384 + db*8192 + 4096 + wb);
    };
    stage(0, 0);
    __syncthreads();
#else
    int4 va0, va1, vb0, vb1;
    auto stage_load = [&](int kt){
        const int k0 = kt * 32;
        va0 = *(const int4*)(A  + (size_t)(row0 + rA0)      * Kp + k0 + ss0 * 8);
        va1 = *(const int4*)(A  + (size_t)(row0 + rA0 + 64) * Kp + k0 + ss1 * 8);
        vb0 = *(const int4*)(Bt + (size_t)(col0 + bp0)      * Kp + k0 + ss0 * 8);
        vb1 = *(const int4*)(Bt + (size_t)(col0 + bp1)      * Kp + k0 + ss1 * 8);
    };
    auto stage_write = [&](int db){
        *(int4*)(sb + db*8192 + (rA0)*64 + sA0*16)            = va0;
        *(int4*)(sb + db*8192 + 4096 + (rA0)*64 + sA0*16)     = va1;
        *(int4*)(sb + 16384 + db*8192 + (rA0)*64 + sA0*16)    = vb0;
        *(int4*)(sb + 16384 + db*8192 + 4096 + (rA0)*64 + sA0*16) = vb1;
    };
    stage_load(0); stage_write(0);
    __syncthreads();
#endif

    for (int kt = 0; kt < nt; ++kt){
        const int db = kt & 1;
#if ASYNC_LDS
        if (kt + 1 < nt) stage(kt + 1, db ^ 1);     // async into other buffer
#else
        if (kt + 1 < nt) stage_load(kt + 1);
#endif

        f16x8 af[2], bf[8];
        #pragma unroll
        for (int m = 0; m < 2; ++m){
            int row = w * 32 + m * 16 + fr;
            af[m] = *(const f16x8*)&smem[aoff(db, row, fq)];
        }
        #pragma unroll
        for (int n = 0; n < 8; ++n){
            int col = n * 16 + fr;                  // LDS row (permuted)
            bf[n] = *(const f16x8*)&smem[boff(db, col, fq)];
        }
        #pragma unroll
        for (int m = 0; m < 2; ++m)
            #pragma unroll
            for (int n = 0; n < 8; ++n)
                acc[m][n] = __builtin_amdgcn_mfma_f32_16x16x32_f16(af[m], bf[n], acc[m][n], 0, 0, 0);

#if !ASYNC_LDS
        if (kt + 1 < nt) stage_write(db ^ 1);
#endif
        __syncthreads();
    }

    // lane fr owns actual cols 8*fr..8*fr+7 (acc[m][n][r] -> col 8*fr+n)
    #pragma unroll
    for (int m = 0; m < 2; ++m){
        int rowb = row0 + w * 32 + m * 16 + fq * 4;
        #pragma unroll
        for (int r = 0; r < 4; ++r){
            int row = rowb + r;
            if (row < Mvalid){
                float v8[8];
                #pragma unroll
                for (int n = 0; n < 8; ++n) v8[n] = acc[m][n][r];
                uint2 pk = f2fp8x8(v8);
                *(uint2*)(Cq + (size_t)row * HC + col0 + 8 * fr) = pk;
            }
        }
    }
}

// per-node attention logits from fp8 htq (lane -> cols 4l..4l+3)
__global__ __launch_bounds__(256) void al_kernel(const u8* __restrict__ htq,
                                                 const float* __restrict__ a_s,
                                                 const float* __restrict__ a_d,
                                                 float* __restrict__ als,
                                                 float* __restrict__ ald){
    int wave = threadIdx.x >> 6, lane = threadIdx.x & 63;
    int n = blockIdx.x * 4 + wave;
    if (n >= N_NODES) return;
    const unsigned u = *(const unsigned*)(htq + (size_t)n * HC + 4 * lane);
    f32x4 f = fp8x4tof(u);
    const float4 as4 = *(const float4*)(a_s + 4 * lane);
    const float4 ad4 = *(const float4*)(a_d + 4 * lane);
    float ps = f.x * as4.x + f.y * as4.y + f.z * as4.z + f.w * as4.w;
    float pd = f.x * ad4.x + f.y * ad4.y + f.z * ad4.z + f.w * ad4.w;
    #pragma unroll
    for (int o = 8; o >= 1; o >>= 1){
        ps += __shfl_xor(ps, o, 64);
        pd += __shfl_xor(pd, o, 64);
    }
    if ((lane & 15) == 0){
        als[n * 4 + (lane >> 4)] = ps;
        ald[n * 4 + (lane >> 4)] = pd;
    }
}

// one wave per destination node: no-max softmax + fp8 gather, 8-deep chunks,
// 2 shuffles/edge.
__global__ __launch_bounds__(256) void aggregate_kernel(const u8* __restrict__ htq,
                                                        const float* __restrict__ als,
                                                        const float* __restrict__ ald,
                                                        const int* __restrict__ rs,
                                                        const int* __restrict__ csr,
                                                        const float* __restrict__ bias,
                                                        __half* __restrict__ hf,
                                                        int do_relu){
    int wave = threadIdx.x >> 6, lane = threadIdx.x & 63;
    int n = blockIdx.x * 4 + wave;
    if (n >= N_NODES) return;
    const int s0 = rs[n], s1 = rs[n + 1];
    const int deg = s1 - s0;
    const int hsel = lane >> 4;             // head owning cols 4l..4l+3
    const float4 adv = *(const float4*)(ald + (size_t)n * 4);
    const float ad0 = adv.x, ad1 = adv.y, ad2 = adv.z, ad3 = adv.w;

    float4 acc = {0.f, 0.f, 0.f, 0.f};
    float sm0 = 0.f, sm1 = 0.f, sm2 = 0.f, sm3 = 0.f;

    if (deg <= 64){
        const int i = s0 + lane;
        int s = 0;
        float ex0 = 0.f, ex1 = 0.f, ex2 = 0.f, ex3 = 0.f;
        if (i < s1){
            s = csr[i];
            float4 a = *(const float4*)(als + (size_t)s * 4);
            ex0 = __expf(leaky(a.x + ad0));
            ex1 = __expf(leaky(a.y + ad1));
            ex2 = __expf(leaky(a.z + ad2));
            ex3 = __expf(leaky(a.w + ad3));
        }
        sm0 = ex0; sm1 = ex1; sm2 = ex2; sm3 = ex3;
        const unsigned psel = (hsel < 2) ? packh2(ex0, ex1) : packh2(ex2, ex3);
        const bool evH = ((hsel & 1) == 0);

        const int dp = (deg + 7) & ~7;
        for (int j = 0; j < dp; j += 8){
            int sj[8]; float aw[8];
            #pragma unroll
            for (int k = 0; k < 8; ++k){
                const int jj = j + k;
                sj[k] = __shfl(s, jj, 64);
                unsigned q = __shfl(psel, jj, 64);
                float2 f2 = unpackh2(q);
                aw[k] = evH ? f2.x : f2.y;
            }
            unsigned u[8];
            #pragma unroll
            for (int k = 0; k < 8; ++k)
                u[k] = *(const unsigned*)(htq + (size_t)sj[k] * HC + 4 * lane);
            #pragma unroll
            for (int k = 0; k < 8; ++k){
                f32x4 f = fp8x4tof(u[k]);
                acc.x += aw[k] * f.x; acc.y += aw[k] * f.y;
                acc.z += aw[k] * f.z; acc.w += aw[k] * f.w;
            }
        }
    } else {
        // slow path (deg > 64): rare, correctness only
        for (int base = s0; base < s1; base += 64){
            const int i = base + lane;
            int s = 0;
            float ex0 = 0.f, ex1 = 0.f, ex2 = 0.f, ex3 = 0.f;
            if (i < s1){
                s = csr[i];
                float4 a = *(const float4*)(als + (size_t)s * 4);
                ex0 = __expf(leaky(a.x + ad0));
                ex1 = __expf(leaky(a.y + ad1));
                ex2 = __expf(leaky(a.z + ad2));
                ex3 = __expf(leaky(a.w + ad3));
            }
            sm0 += ex0; sm1 += ex1; sm2 += ex2; sm3 += ex3;
            const int cnt = min(64, s1 - base);
            for (int j = 0; j < cnt; ++j){
                int   sj = __shfl(s,   j, 64);
                float a0 = __shfl(ex0, j, 64);
                float a1 = __shfl(ex1, j, 64);
                float a2 = __shfl(ex2, j, 64);
                float a3 = __shfl(ex3, j, 64);
                float x0 = (hsel == 0) ? a0 : a1;
                float x1 = (hsel == 2) ? a2 : a3;
                float aw = (hsel < 2) ? x0 : x1;
                unsigned u = *(const unsigned*)(htq + (size_t)sj * HC + 4 * lane);
                f32x4 f = fp8x4tof(u);
                acc.x += aw * f.x; acc.y += aw * f.y;
                acc.z += aw * f.z; acc.w += aw * f.w;
            }
        }
    }

    #pragma unroll
    for (int o = 32; o >= 1; o >>= 1){
        sm0 += __shfl_xor(sm0, o, 64);
        sm1 += __shfl_xor(sm1, o, 64);
        sm2 += __shfl_xor(sm2, o, 64);
        sm3 += __shfl_xor(sm3, o, 64);
    }
    float x0 = (hsel == 0) ? sm0 : sm1;
    float x1 = (hsel == 2) ? sm2 : sm3;
    const float inv = 1.f / (((hsel < 2) ? x0 : x1) + 1e-16f);

    const float4 bv = *(const float4*)(bias + 4 * lane);
    float v0 = acc.x * inv + bv.x;
    float v1 = acc.y * inv + bv.y;
    float v2 = acc.z * inv + bv.z;
    float v3 = acc.w * inv + bv.w;
    if (do_relu){
        v0 = fmaxf(v0, 0.f); v1 = fmaxf(v1, 0.f);
        v2 = fmaxf(v2, 0.f); v3 = fmaxf(v3, 0.f);
    }
    ushort4 p;
    p.x = __half_as_ushort(__float2half(v0));
    p.y = __half_as_ushort(__float2half(v1));
    p.z = __half_as_ushort(__float2half(v2));
    p.w = __half_as_ushort(__float2half(v3));
    *(ushort4*)((u16*)hf + (size_t)n * HC + 4 * lane) = p;
}

__global__ void gstart_kernel(const int* __restrict__ batch, int* __restrict__ gstart){
    int g = blockIdx.x * blockDim.x + threadIdx.x;
    if (g > G_GRAPHS) return;
    int lo = 0, hi = N_NODES;
    while (lo < hi){
        int mid = (lo + hi) >> 1;
        if (batch[mid] < g) lo = mid + 1; else hi = mid;
    }
    gstart[g] = lo;
}

__global__ __launch_bounds__(256) void pool_kernel(const __half* __restrict__ h,
                                                   const int* __restrict__ gstart,
                                                   float* __restrict__ pooled){
    int g = blockIdx.x, t = threadIdx.x;
    int s0 = gstart[g], s1 = gstart[g + 1];
    float sum = 0.f;
    for (int n = s0; n < s1; ++n) sum += __half2float(h[(size_t)n * HC + t]);
    pooled[g * HC + t] = sum / fmaxf((float)(s1 - s0), 1.f);
}

__global__ void mlp1_kernel(const float* __restrict__ pooled, const float* __restrict__ Wm1,
                            const float* __restrict__ bm1, float* __restrict__ z){
    int g = blockIdx.x, j = threadIdx.x;
    if (j >= NHID) return;
    float acc = bm1[j];
    for (int k = 0; k < HC; ++k) acc += pooled[g * HC + k] * Wm1[(size_t)k * NHID + j];
    z[g * NHID + j] = fmaxf(acc, 0.f);
}

__global__ void mlp2_kernel(const float* __restrict__ z, const float* __restrict__ Wm2,
                            const float* __restrict__ bm2, float* __restrict__ out){
    int g = blockIdx.x, j = threadIdx.x;
    float acc = bm2[j];
    for (int k = 0; k < NHID; ++k) acc += z[g * NHID + k] * Wm2[(size_t)k * NOUT + j];
    out[g * NOUT + j] = acc;
}

extern "C" void kernel_launch(void* const* d_in, const int* in_sizes, int n_in,
                              void* d_out, int out_size, void* d_ws, size_t ws_size,
                              hipStream_t stream){
    const float* x    = (const float*)d_in[0];
    const int*   ei   = (const int*)  d_in[1];
    const int*   batch= (const int*)  d_in[2];
    const float* W1   = (const float*)d_in[3];
    const float* a1s  = (const float*)d_in[4];
    const float* a1d  = (const float*)d_in[5];
    const float* b1   = (const float*)d_in[6];
    const float* W2   = (const float*)d_in[7];
    const float* a2s  = (const float*)d_in[8];
    const float* a2d  = (const float*)d_in[9];
    const float* b2   = (const float*)d_in[10];
    const float* W3   = (const float*)d_in[11];
    const float* a3s  = (const float*)d_in[12];
    const float* a3d  = (const float*)d_in[13];
    const float* b3   = (const float*)d_in[14];
    const float* Wm1  = (const float*)d_in[15];
    const float* bm1  = (const float*)d_in[16];
    const float* Wm2  = (const float*)d_in[17];
    const float* bm2  = (const float*)d_in[18];
    float* out = (float*)d_out;

    char* ws = (char*)d_ws;
    size_t off = 0;
    auto alloc = [&](size_t bytes)->char*{
        char* p = ws + off;
        off = (off + bytes + 255) & ~(size_t)255;
        return p;
    };
    __half* xf    = (__half*)alloc((size_t)M_PAD * K1P * 2);    // reused as layer-3 out
    __half* hf    = (__half*)alloc((size_t)M_PAD * HC * 2);
    u8*     htq   = (u8*)   alloc((size_t)N_NODES * HC);
    __half* hout  = xf;                                         // layer-3 output (xf dead)
    __half* wt1   = (__half*)alloc((size_t)HC * K1P * 2);
    __half* wt2   = (__half*)alloc((size_t)HC * HC * 2);
    __half* wt3   = (__half*)alloc((size_t)HC * HC * 2);
    float* als    = (float*)alloc((size_t)N_NODES * 4 * 4);
    float* ald    = (float*)alloc((size_t)N_NODES * 4 * 4);
    int*   counts = (int*)  alloc((size_t)N_NODES * 4);
    int*   rs     = (int*)  alloc((size_t)(N_NODES + 1) * 4);
    int*   cursor = (int*)  alloc((size_t)N_NODES * 4);
    int*   csr    = (int*)  alloc((size_t)ETOT * 4);
    int*   bsum   = (int*)  alloc(256 * 4);
    int*   boffs  = (int*)  alloc(256 * 4);
    int*   gstart = (int*)  alloc((size_t)(G_GRAPHS + 1) * 4);
    float* pooled = (float*)alloc((size_t)G_GRAPHS * HC * 4);
    float* zbuf   = (float*)alloc((size_t)G_GRAPHS * NHID * 4);

    conv_x_kernel<<<M_PAD, K1P, 0, stream>>>(x, xf);
    conv_w_kernel<<<HC, K1P, 0, stream>>>(W1, wt1, FIN, K1P);
    conv_w_kernel<<<HC, HC, 0, stream>>>(W2, wt2, HC, HC);
    conv_w_kernel<<<HC, HC, 0, stream>>>(W3, wt3, HC, HC);
    pad_h_kernel<<<M_PAD - N_NODES, HC, 0, stream>>>(hf);

    zero_i32<<<(N_NODES + 255) / 256, 256, 0, stream>>>(counts, N_NODES);
    hist_kernel<<<8 * NCHUNK, 256, 0, stream>>>(ei, counts);
    bsum_kernel<<<NBLK, 256, 0, stream>>>(counts, bsum);
    bscan_kernel<<<1, 256, 0, stream>>>(bsum, boffs, rs);
    offsets_kernel<<<NBLK, 256, 0, stream>>>(counts, boffs, rs, cursor);
    scatter_kernel<<<8 * NCHUNK, 256, 0, stream>>>(ei, cursor, csr);
    gstart_kernel<<<3, 256, 0, stream>>>(batch, gstart);

    const int GG = 8 * 98;                 // 784 blocks, XCD row-pair mapping

    // layer 1
    gemm_fp16<<<GG, 256, 0, stream>>>(xf, wt1, htq, K1P, N_NODES);
    al_kernel<<<(N_NODES + 3) / 4, 256, 0, stream>>>(htq, a1s, a1d, als, ald);
    aggregate_kernel<<<(N_NODES + 3) / 4, 256, 0, stream>>>(htq, als, ald, rs, csr,
                                                            b1, hf, 1);
    // layer 2
    gemm_fp16<<<GG, 256, 0, stream>>>(hf, wt2, htq, HC, N_NODES);
    al_kernel<<<(N_NODES + 3) / 4, 256, 0, stream>>>(htq, a2s, a2d, als, ald);
    aggregate_kernel<<<(N_NODES + 3) / 4, 256, 0, stream>>>(htq, als, ald, rs, csr,
                                                            b2, hf, 1);
    // layer 3 (output into hout = xf)
    gemm_fp16<<<GG, 256, 0, stream>>>(hf, wt3, htq, HC, N_NODES);
    al_kernel<<<(N_NODES + 3) / 4, 256, 0, stream>>>(htq, a3s, a3d, als, ald);
    aggregate_kernel<<<(N_NODES + 3) / 4, 256, 0, stream>>>(htq, als, ald, rs, csr,
                                                            b3, hout, 0);

    pool_kernel<<<G_GRAPHS, 256, 0, stream>>>(hout, gstart, pooled);
    mlp1_kernel<<<G_GRAPHS, 320, 0, stream>>>(pooled, Wm1, bm1, zbuf);
    mlp2_kernel<<<G_GRAPHS, 512, 0, stream>>>(zbuf, Wm2, bm2, out);
}

// Round 20
// 362.697 us; speedup vs baseline: 1.0763x; 1.0316x over previous
//
#include <hip/hip_runtime.h>
#include <hip/hip_fp16.h>
#include <hip/hip_fp8.h>
#include <cstdint>

#define N_NODES 50000
#define M_PAD   50048
#define E_EDGES 800000
#define ETOT (E_EDGES + N_NODES)
#define G_GRAPHS 512
#define FIN 300
#define K1P 320
#define HC 256
#define NHID 300
#define NOUT 512
#define NBLK 196               // ceil(N_NODES / 256)
#define ROWB 391               // M_PAD / 128
#define QPX  49                // row-blocks per XCD (8*49 >= 391)
#define DRANGE 6250            // N_NODES / 8 dst-range per XCD
#define NCHUNK 128             // edge chunks per XCD-group
#define CHUNK_E ((ETOT + NCHUNK - 1) / NCHUNK)

typedef unsigned short u16;
typedef unsigned char  u8;
typedef __attribute__((ext_vector_type(8))) _Float16 f16x8;
typedef __attribute__((ext_vector_type(4))) float f32x4;
typedef __attribute__((ext_vector_type(2))) float f32x2;

__device__ __forceinline__ float leaky(float x){ return x > 0.f ? x : 0.2f * x; }

#if __has_builtin(__builtin_amdgcn_cvt_pk_fp8_f32) && __has_builtin(__builtin_amdgcn_cvt_pk_f32_fp8)
#define FP8_HW 1
#else
#define FP8_HW 0
#endif

#if __has_builtin(__builtin_amdgcn_global_load_lds)
#define ASYNC_LDS 1
#define GLDS(g, l) __builtin_amdgcn_global_load_lds( \
    (const __attribute__((address_space(1))) void*)(g), \
    (__attribute__((address_space(3))) void*)(l), 16, 0, 0)
#else
#define ASYNC_LDS 0
#endif

__device__ __forceinline__ u8 f2fp8(float v){
#if FP8_HW
    int b = __builtin_amdgcn_cvt_pk_fp8_f32(v, v, 0, false);
    return (u8)(b & 0xff);
#else
    return (u8)__hip_cvt_float_to_fp8(v, __HIP_SATFINITE, __HIP_E4M3);
#endif
}

// pack 8 f32 -> 8 fp8 bytes (two u32)
__device__ __forceinline__ uint2 f2fp8x8(const float* v){
#if FP8_HW
    int lo = 0, hi = 0;
    lo = __builtin_amdgcn_cvt_pk_fp8_f32(v[0], v[1], lo, false);
    lo = __builtin_amdgcn_cvt_pk_fp8_f32(v[2], v[3], lo, true);
    hi = __builtin_amdgcn_cvt_pk_fp8_f32(v[4], v[5], hi, false);
    hi = __builtin_amdgcn_cvt_pk_fp8_f32(v[6], v[7], hi, true);
    uint2 r; r.x = (unsigned)lo; r.y = (unsigned)hi; return r;
#else
    unsigned lo = 0, hi = 0;
    #pragma unroll
    for (int k = 0; k < 4; ++k) lo |= ((unsigned)f2fp8(v[k])) << (8 * k);
    #pragma unroll
    for (int k = 0; k < 4; ++k) hi |= ((unsigned)f2fp8(v[4 + k])) << (8 * k);
    uint2 r; r.x = lo; r.y = hi; return r;
#endif
}

// decode 4 packed fp8 (one u32) -> 4 floats
__device__ __forceinline__ f32x4 fp8x4tof(unsigned u){
#if FP8_HW
    f32x2 lo = __builtin_amdgcn_cvt_pk_f32_fp8(u, false);
    f32x2 hi = __builtin_amdgcn_cvt_pk_f32_fp8(u, true);
    return (f32x4){lo.x, lo.y, hi.x, hi.y};
#else
    auto d1 = [](u8 b)->float{
        __half_raw hr = __hip_cvt_fp8_to_halfraw((__hip_fp8_storage_t)b, __HIP_E4M3);
        return __half2float(*reinterpret_cast<__half*>(&hr));
    };
    return (f32x4){d1((u8)(u & 0xff)), d1((u8)((u >> 8) & 0xff)),
                   d1((u8)((u >> 16) & 0xff)), d1((u8)((u >> 24) & 0xff))};
#endif
}

__device__ __forceinline__ unsigned packh2(float a, float b){
    __half2 h = __floats2half2_rn(a, b);
    return *reinterpret_cast<unsigned*>(&h);
}
__device__ __forceinline__ float2 unpackh2(unsigned u){
    __half2 h = *reinterpret_cast<__half2*>(&u);
    return __half22float2(h);
}

__global__ void zero_i32(int* __restrict__ p, int n){
    int i = blockIdx.x * blockDim.x + threadIdx.x;
    if (i < n) p[i] = 0;
}

// XCD-partitioned histogram
__global__ __launch_bounds__(256) void hist_kernel(const int* __restrict__ ei,
                                                   int* __restrict__ counts){
    const int xcd = blockIdx.x & 7, chunk = blockIdx.x >> 3;
    const int lo = xcd * DRANGE, hi = lo + DRANGE;
    const int e0 = chunk * CHUNK_E;
    const int e1 = min(e0 + CHUNK_E, ETOT);
    for (int i = e0 + threadIdx.x; i < e1; i += 256){
        int d = (i < E_EDGES) ? ei[E_EDGES + i] : (i - E_EDGES);
        if (d >= lo && d < hi) atomicAdd(&counts[d], 1);
    }
}

// XCD-partitioned scatter
__global__ __launch_bounds__(256) void scatter_kernel(const int* __restrict__ ei,
                                                      int* __restrict__ cursor,
                                                      int* __restrict__ csr_src){
    const int xcd = blockIdx.x & 7, chunk = blockIdx.x >> 3;
    const int lo = xcd * DRANGE, hi = lo + DRANGE;
    const int e0 = chunk * CHUNK_E;
    const int e1 = min(e0 + CHUNK_E, ETOT);
    for (int i = e0 + threadIdx.x; i < e1; i += 256){
        int d = (i < E_EDGES) ? ei[E_EDGES + i] : (i - E_EDGES);
        if (d >= lo && d < hi){
            int s = (i < E_EDGES) ? ei[i] : (i - E_EDGES);
            int pos = atomicAdd(&cursor[d], 1);
            csr_src[pos] = s;
        }
    }
}

// ---- two-level scan ---------------------------------------------------------

__global__ __launch_bounds__(256) void bsum_kernel(const int* __restrict__ counts,
                                                   int* __restrict__ bsum){
    int b = blockIdx.x, t = threadIdx.x;
    int i = b * 256 + t;
    int v = (i < N_NODES) ? counts[i] : 0;
    #pragma unroll
    for (int o = 32; o >= 1; o >>= 1) v += __shfl_xor(v, o, 64);
    __shared__ int ws[4];
    if ((t & 63) == 0) ws[t >> 6] = v;
    __syncthreads();
    if (t == 0) bsum[b] = ws[0] + ws[1] + ws[2] + ws[3];
}

__global__ __launch_bounds__(256) void bscan_kernel(const int* __restrict__ bsum,
                                                    int* __restrict__ boff,
                                                    int* __restrict__ rs){
    int t = threadIdx.x;
    int v = (t < NBLK) ? bsum[t] : 0;
    __shared__ int sd[256];
    sd[t] = v;
    __syncthreads();
    for (int off = 1; off < 256; off <<= 1){
        int u = (t >= off) ? sd[t - off] : 0;
        __syncthreads();
        sd[t] += u;
        __syncthreads();
    }
    if (t < NBLK) boff[t] = sd[t] - v;     // exclusive
    if (t == 0) rs[N_NODES] = ETOT;
}

__global__ __launch_bounds__(256) void offsets_kernel(const int* __restrict__ counts,
                                                      const int* __restrict__ boff,
                                                      int* __restrict__ rs,
                                                      int* __restrict__ cursor){
    int b = blockIdx.x, t = threadIdx.x;
    int i = b * 256 + t;
    int v = (i < N_NODES) ? counts[i] : 0;
    __shared__ int sd[256];
    sd[t] = v;
    __syncthreads();
    for (int off = 1; off < 256; off <<= 1){
        int u = (t >= off) ? sd[t - off] : 0;
        __syncthreads();
        sd[t] += u;
        __syncthreads();
    }
    if (i < N_NODES){
        int o = boff[b] + sd[t] - v;
        rs[i] = o; cursor[i] = o;
    }
}

// ---- conversion kernels: fp32 -> fp16 ---------------------------------------

__global__ void conv_x_kernel(const float* __restrict__ x, __half* __restrict__ xf){
    int row = blockIdx.x, t = threadIdx.x;          // grid M_PAD, block 320
    float v = 0.f;
    if (row < N_NODES && t < FIN) v = x[(size_t)row * FIN + t];
    xf[(size_t)row * K1P + t] = __float2half(v);
}

__global__ void conv_w_kernel(const float* __restrict__ W, __half* __restrict__ wf,
                              int K, int Kp){
    int col = blockIdx.x, k = threadIdx.x;          // grid 256, block Kp
    float v = (k < K) ? W[(size_t)k * HC + col] : 0.f;
    wf[(size_t)col * Kp + k] = __float2half(v);
}

__global__ void pad_h_kernel(__half* __restrict__ hf){
    int row = N_NODES + blockIdx.x;                 // grid 48, block 256
    int t = threadIdx.x;
    hf[(size_t)row * HC + t] = __float2half(0.f);
}

// ---- fp16 MFMA GEMM, tile 128x128, fp8 output, fused attention logits -------
// B cols permuted in LDS (lane fr owns consecutive cols 8fr..8fr+7, one head);
// block covers 2 full heads -> per-row logit dot reduces over 8 lanes, plain
// stores to als/ald (each (row,head) produced by exactly one block).
__global__ __launch_bounds__(256) void gemm_fp16(const __half* __restrict__ A,
                                                 const __half* __restrict__ Bt,
                                                 u8* __restrict__ Cq,
                                                 const float* __restrict__ a_s,
                                                 const float* __restrict__ a_d,
                                                 float* __restrict__ als,
                                                 float* __restrict__ ald,
                                                 int Kp, int Mvalid){
    const int wgid = blockIdx.x;
    const int x    = wgid & 7, i = wgid >> 3;       // i in 0..97
    const int y    = x * QPX + (i >> 1);
    if (y >= ROWB) return;
    const int cx   = i & 1;
    const int col0 = cx * 128;
    const int row0 = y * 128;

    __shared__ u16 smem[16384];                     // 32 KB
    char* sb = (char*)smem;
    const int t    = threadIdx.x;
    const int lane = t & 63;
    const int w    = t >> 6;                        // wave 0..3 -> rows w*32..
    const int fr   = lane & 15, fq = lane >> 4;

    const int rA0 = t >> 2, sA0 = t & 3;            // LDS rows 0..63 (+64)
    const int ss0 = sA0 ^ ((rA0 >> 1) & 3);         // pre-swizzled source slot
    const int ss1 = sA0 ^ (((rA0 + 64) >> 1) & 3);
    const int wb  = (t & ~63) * 16;                 // wave-uniform byte base

    // B-col permutation: LDS row p <- global B row col0 + 8*(p&15) + (p>>4)
    const int bp0 = 8 * (rA0 & 15) + (rA0 >> 4);
    const int bp1 = 8 * ((rA0 + 64) & 15) + ((rA0 + 64) >> 4);

    auto aoff = [](int db, int row, int slot)->int{ // u16-element offset (reads)
        return db * 4096 + row * 32 + ((slot ^ ((row >> 1) & 3)) * 8);
    };
    auto boff = [](int db, int row, int slot)->int{
        return 8192 + db * 4096 + row * 32 + ((slot ^ ((row >> 1) & 3)) * 8);
    };

    f32x4 acc[2][8];
    #pragma unroll
    for (int m = 0; m < 2; ++m)
        #pragma unroll
        for (int n = 0; n < 8; ++n) acc[m][n] = (f32x4){0.f, 0.f, 0.f, 0.f};

    const int nt = Kp >> 5;

#if ASYNC_LDS
    auto stage = [&](int kt, int db){
        const int k0 = kt * 32;
        GLDS(A  + (size_t)(row0 + rA0)      * Kp + k0 + ss0 * 8, sb + db*8192 + wb);
        GLDS(A  + (size_t)(row0 + rA0 + 64) * Kp + k0 + ss1 * 8, sb + db*8192 + 4096 + wb);
        GLDS(Bt + (size_t)(col0 + bp0)      * Kp + k0 + ss0 * 8, sb + 16384 + db*8192 + wb);
        GLDS(Bt + (size_t)(col0 + bp1)      * Kp + k0 + ss1 * 8, sb + 16384 + db*8192 + 4096 + wb);
    };
    stage(0, 0);
    __syncthreads();
#else
    int4 va0, va1, vb0, vb1;
    auto stage_load = [&](int kt){
        const int k0 = kt * 32;
        va0 = *(const int4*)(A  + (size_t)(row0 + rA0)      * Kp + k0 + ss0 * 8);
        va1 = *(const int4*)(A  + (size_t)(row0 + rA0 + 64) * Kp + k0 + ss1 * 8);
        vb0 = *(const int4*)(Bt + (size_t)(col0 + bp0)      * Kp + k0 + ss0 * 8);
        vb1 = *(const int4*)(Bt + (size_t)(col0 + bp1)      * Kp + k0 + ss1 * 8);
    };
    auto stage_write = [&](int db){
        *(int4*)(sb + db*8192 + (rA0)*64 + sA0*16)            = va0;
        *(int4*)(sb + db*8192 + 4096 + (rA0)*64 + sA0*16)     = va1;
        *(int4*)(sb + 16384 + db*8192 + (rA0)*64 + sA0*16)    = vb0;
        *(int4*)(sb + 16384 + db*8192 + 4096 + (rA0)*64 + sA0*16) = vb1;
    };
    stage_load(0); stage_write(0);
    __syncthreads();
#endif

    for (int kt = 0; kt < nt; ++kt){
        const int db = kt & 1;
#if ASYNC_LDS
        if (kt + 1 < nt) stage(kt + 1, db ^ 1);     // async into other buffer
#else
        if (kt + 1 < nt) stage_load(kt + 1);
#endif

        f16x8 af[2], bf[8];
        #pragma unroll
        for (int m = 0; m < 2; ++m){
            int row = w * 32 + m * 16 + fr;
            af[m] = *(const f16x8*)&smem[aoff(db, row, fq)];
        }
        #pragma unroll
        for (int n = 0; n < 8; ++n){
            int col = n * 16 + fr;                  // LDS row (permuted)
            bf[n] = *(const f16x8*)&smem[boff(db, col, fq)];
        }
        #pragma unroll
        for (int m = 0; m < 2; ++m)
            #pragma unroll
            for (int n = 0; n < 8; ++n)
                acc[m][n] = __builtin_amdgcn_mfma_f32_16x16x32_f16(af[m], bf[n], acc[m][n], 0, 0, 0);

#if !ASYNC_LDS
        if (kt + 1 < nt) stage_write(db ^ 1);
#endif
        __syncthreads();
    }

    // Epilogue: lane fr owns actual cols 8*fr..8*fr+7 (one head's slice).
    const int head = 2 * cx + (fr >> 3);
    float as8[8], ad8[8];
    #pragma unroll
    for (int n = 0; n < 8; ++n){
        as8[n] = a_s[col0 + 8 * fr + n];
        ad8[n] = a_d[col0 + 8 * fr + n];
    }

    #pragma unroll
    for (int m = 0; m < 2; ++m){
        int rowb = row0 + w * 32 + m * 16 + fq * 4;
        #pragma unroll
        for (int r = 0; r < 4; ++r){
            int row = rowb + r;
            float v8[8];
            #pragma unroll
            for (int n = 0; n < 8; ++n) v8[n] = acc[m][n][r];
            if (row < Mvalid){
                uint2 pk = f2fp8x8(v8);
                *(uint2*)(Cq + (size_t)row * HC + col0 + 8 * fr) = pk;
            }
            float ps = 0.f, pd = 0.f;
            #pragma unroll
            for (int n = 0; n < 8; ++n){ ps += v8[n] * as8[n]; pd += v8[n] * ad8[n]; }
            #pragma unroll
            for (int o = 1; o <= 4; o <<= 1){
                ps += __shfl_xor(ps, o, 64);
                pd += __shfl_xor(pd, o, 64);
            }
            if ((fr & 7) == 0 && row < Mvalid){
                als[row * 4 + head] = ps;
                ald[row * 4 + head] = pd;
            }
        }
    }
}

// one wave per destination node: no-max softmax + fp8 gather, 8-deep chunks,
// 2 shuffles/edge.
__global__ __launch_bounds__(256) void aggregate_kernel(const u8* __restrict__ htq,
                                                        const float* __restrict__ als,
                                                        const float* __restrict__ ald,
                                                        const int* __restrict__ rs,
                                                        const int* __restrict__ csr,
                                                        const float* __restrict__ bias,
                                                        __half* __restrict__ hf,
                                                        int do_relu){
    int wave = threadIdx.x >> 6, lane = threadIdx.x & 63;
    int n = blockIdx.x * 4 + wave;
    if (n >= N_NODES) return;
    const int s0 = rs[n], s1 = rs[n + 1];
    const int deg = s1 - s0;
    const int hsel = lane >> 4;             // head owning cols 4l..4l+3
    const float4 adv = *(const float4*)(ald + (size_t)n * 4);
    const float ad0 = adv.x, ad1 = adv.y, ad2 = adv.z, ad3 = adv.w;

    float4 acc = {0.f, 0.f, 0.f, 0.f};
    float sm0 = 0.f, sm1 = 0.f, sm2 = 0.f, sm3 = 0.f;

    if (deg <= 64){
        const int i = s0 + lane;
        int s = 0;
        float ex0 = 0.f, ex1 = 0.f, ex2 = 0.f, ex3 = 0.f;
        if (i < s1){
            s = csr[i];
            float4 a = *(const float4*)(als + (size_t)s * 4);
            ex0 = __expf(leaky(a.x + ad0));
            ex1 = __expf(leaky(a.y + ad1));
            ex2 = __expf(leaky(a.z + ad2));
            ex3 = __expf(leaky(a.w + ad3));
        }
        sm0 = ex0; sm1 = ex1; sm2 = ex2; sm3 = ex3;
        const unsigned psel = (hsel < 2) ? packh2(ex0, ex1) : packh2(ex2, ex3);
        const bool evH = ((hsel & 1) == 0);

        const int dp = (deg + 7) & ~7;
        for (int j = 0; j < dp; j += 8){
            int sj[8]; float aw[8];
            #pragma unroll
            for (int k = 0; k < 8; ++k){
                const int jj = j + k;
                sj[k] = __shfl(s, jj, 64);
                unsigned q = __shfl(psel, jj, 64);
                float2 f2 = unpackh2(q);
                aw[k] = evH ? f2.x : f2.y;
            }
            unsigned u[8];
            #pragma unroll
            for (int k = 0; k < 8; ++k)
                u[k] = *(const unsigned*)(htq + (size_t)sj[k] * HC + 4 * lane);
            #pragma unroll
            for (int k = 0; k < 8; ++k){
                f32x4 f = fp8x4tof(u[k]);
                acc.x += aw[k] * f.x; acc.y += aw[k] * f.y;
                acc.z += aw[k] * f.z; acc.w += aw[k] * f.w;
            }
        }
    } else {
        // slow path (deg > 64): rare, correctness only
        for (int base = s0; base < s1; base += 64){
            const int i = base + lane;
            int s = 0;
            float ex0 = 0.f, ex1 = 0.f, ex2 = 0.f, ex3 = 0.f;
            if (i < s1){
                s = csr[i];
                float4 a = *(const float4*)(als + (size_t)s * 4);
                ex0 = __expf(leaky(a.x + ad0));
                ex1 = __expf(leaky(a.y + ad1));
                ex2 = __expf(leaky(a.z + ad2));
                ex3 = __expf(leaky(a.w + ad3));
            }
            sm0 += ex0; sm1 += ex1; sm2 += ex2; sm3 += ex3;
            const int cnt = min(64, s1 - base);
            for (int j = 0; j < cnt; ++j){
                int   sj = __shfl(s,   j, 64);
                float a0 = __shfl(ex0, j, 64);
                float a1 = __shfl(ex1, j, 64);
                float a2 = __shfl(ex2, j, 64);
                float a3 = __shfl(ex3, j, 64);
                float x0 = (hsel == 0) ? a0 : a1;
                float x1 = (hsel == 2) ? a2 : a3;
                float aw = (hsel < 2) ? x0 : x1;
                unsigned u = *(const unsigned*)(htq + (size_t)sj * HC + 4 * lane);
                f32x4 f = fp8x4tof(u);
                acc.x += aw * f.x; acc.y += aw * f.y;
                acc.z += aw * f.z; acc.w += aw * f.w;
            }
        }
    }

    #pragma unroll
    for (int o = 32; o >= 1; o >>= 1){
        sm0 += __shfl_xor(sm0, o, 64);
        sm1 += __shfl_xor(sm1, o, 64);
        sm2 += __shfl_xor(sm2, o, 64);
        sm3 += __shfl_xor(sm3, o, 64);
    }
    float x0 = (hsel == 0) ? sm0 : sm1;
    float x1 = (hsel == 2) ? sm2 : sm3;
    const float inv = 1.f / (((hsel < 2) ? x0 : x1) + 1e-16f);

    const float4 bv = *(const float4*)(bias + 4 * lane);
    float v0 = acc.x * inv + bv.x;
    float v1 = acc.y * inv + bv.y;
    float v2 = acc.z * inv + bv.z;
    float v3 = acc.w * inv + bv.w;
    if (do_relu){
        v0 = fmaxf(v0, 0.f); v1 = fmaxf(v1, 0.f);
        v2 = fmaxf(v2, 0.f); v3 = fmaxf(v3, 0.f);
    }
    ushort4 p;
    p.x = __half_as_ushort(__float2half(v0));
    p.y = __half_as_ushort(__float2half(v1));
    p.z = __half_as_ushort(__float2half(v2));
    p.w = __half_as_ushort(__float2half(v3));
    *(ushort4*)((u16*)hf + (size_t)n * HC + 4 * lane) = p;
}

__global__ void gstart_kernel(const int* __restrict__ batch, int* __restrict__ gstart){
    int g = blockIdx.x * blockDim.x + threadIdx.x;
    if (g > G_GRAPHS) return;
    int lo = 0, hi = N_NODES;
    while (lo < hi){
        int mid = (lo + hi) >> 1;
        if (batch[mid] < g) lo = mid + 1; else hi = mid;
    }
    gstart[g] = lo;
}

__global__ __launch_bounds__(256) void pool_kernel(const __half* __restrict__ h,
                                                   const int* __restrict__ gstart,
                                                   float* __restrict__ pooled){
    int g = blockIdx.x, t = threadIdx.x;
    int s0 = gstart[g], s1 = gstart[g + 1];
    float sum = 0.f;
    for (int n = s0; n < s1; ++n) sum += __half2float(h[(size_t)n * HC + t]);
    pooled[g * HC + t] = sum / fmaxf((float)(s1 - s0), 1.f);
}

__global__ void mlp1_kernel(const float* __restrict__ pooled, const float* __restrict__ Wm1,
                            const float* __restrict__ bm1, float* __restrict__ z){
    int g = blockIdx.x, j = threadIdx.x;
    if (j >= NHID) return;
    float acc = bm1[j];
    for (int k = 0; k < HC; ++k) acc += pooled[g * HC + k] * Wm1[(size_t)k * NHID + j];
    z[g * NHID + j] = fmaxf(acc, 0.f);
}

__global__ void mlp2_kernel(const float* __restrict__ z, const float* __restrict__ Wm2,
                            const float* __restrict__ bm2, float* __restrict__ out){
    int g = blockIdx.x, j = threadIdx.x;
    float acc = bm2[j];
    for (int k = 0; k < NHID; ++k) acc += z[g * NHID + k] * Wm2[(size_t)k * NOUT + j];
    out[g * NOUT + j] = acc;
}

extern "C" void kernel_launch(void* const* d_in, const int* in_sizes, int n_in,
                              void* d_out, int out_size, void* d_ws, size_t ws_size,
                              hipStream_t stream){
    const float* x    = (const float*)d_in[0];
    const int*   ei   = (const int*)  d_in[1];
    const int*   batch= (const int*)  d_in[2];
    const float* W1   = (const float*)d_in[3];
    const float* a1s  = (const float*)d_in[4];
    const float* a1d  = (const float*)d_in[5];
    const float* b1   = (const float*)d_in[6];
    const float* W2   = (const float*)d_in[7];
    const float* a2s  = (const float*)d_in[8];
    const float* a2d  = (const float*)d_in[9];
    const float* b2   = (const float*)d_in[10];
    const float* W3   = (const float*)d_in[11];
    const float* a3s  = (const float*)d_in[12];
    const float* a3d  = (const float*)d_in[13];
    const float* b3   = (const float*)d_in[14];
    const float* Wm1  = (const float*)d_in[15];
    const float* bm1  = (const float*)d_in[16];
    const float* Wm2  = (const float*)d_in[17];
    const float* bm2  = (const float*)d_in[18];
    float* out = (float*)d_out;

    char* ws = (char*)d_ws;
    size_t off = 0;
    auto alloc = [&](size_t bytes)->char*{
        char* p = ws + off;
        off = (off + bytes + 255) & ~(size_t)255;
        return p;
    };
    __half* xf    = (__half*)alloc((size_t)M_PAD * K1P * 2);    // reused as layer-3 out
    __half* hf    = (__half*)alloc((size_t)M_PAD * HC * 2);
    u8*     htq   = (u8*)   alloc((size_t)N_NODES * HC);
    __half* hout  = xf;                                         // layer-3 output (xf dead)
    __half* wt1   = (__half*)alloc((size_t)HC * K1P * 2);
    __half* wt2   = (__half*)alloc((size_t)HC * HC * 2);
    __half* wt3   = (__half*)alloc((size_t)HC * HC * 2);
    float* als    = (float*)alloc((size_t)N_NODES * 4 * 4);
    float* ald    = (float*)alloc((size_t)N_NODES * 4 * 4);
    int*   counts = (int*)  alloc((size_t)N_NODES * 4);
    int*   rs     = (int*)  alloc((size_t)(N_NODES + 1) * 4);
    int*   cursor = (int*)  alloc((size_t)N_NODES * 4);
    int*   csr    = (int*)  alloc((size_t)ETOT * 4);
    int*   bsum   = (int*)  alloc(256 * 4);
    int*   boffs  = (int*)  alloc(256 * 4);
    int*   gstart = (int*)  alloc((size_t)(G_GRAPHS + 1) * 4);
    float* pooled = (float*)alloc((size_t)G_GRAPHS * HC * 4);
    float* zbuf   = (float*)alloc((size_t)G_GRAPHS * NHID * 4);

    conv_x_kernel<<<M_PAD, K1P, 0, stream>>>(x, xf);
    conv_w_kernel<<<HC, K1P, 0, stream>>>(W1, wt1, FIN, K1P);
    conv_w_kernel<<<HC, HC, 0, stream>>>(W2, wt2, HC, HC);
    conv_w_kernel<<<HC, HC, 0, stream>>>(W3, wt3, HC, HC);
    pad_h_kernel<<<M_PAD - N_NODES, HC, 0, stream>>>(hf);

    zero_i32<<<(N_NODES + 255) / 256, 256, 0, stream>>>(counts, N_NODES);
    hist_kernel<<<8 * NCHUNK, 256, 0, stream>>>(ei, counts);
    bsum_kernel<<<NBLK, 256, 0, stream>>>(counts, bsum);
    bscan_kernel<<<1, 256, 0, stream>>>(bsum, boffs, rs);
    offsets_kernel<<<NBLK, 256, 0, stream>>>(counts, boffs, rs, cursor);
    scatter_kernel<<<8 * NCHUNK, 256, 0, stream>>>(ei, cursor, csr);
    gstart_kernel<<<3, 256, 0, stream>>>(batch, gstart);

    const int GG = 8 * 98;                 // 784 blocks, XCD row-pair mapping

    // layer 1 (al fused into GEMM epilogue)
    gemm_fp16<<<GG, 256, 0, stream>>>(xf, wt1, htq, a1s, a1d, als, ald, K1P, N_NODES);
    aggregate_kernel<<<(N_NODES + 3) / 4, 256, 0, stream>>>(htq, als, ald, rs, csr,
                                                            b1, hf, 1);
    // layer 2
    gemm_fp16<<<GG, 256, 0, stream>>>(hf, wt2, htq, a2s, a2d, als, ald, HC, N_NODES);
    aggregate_kernel<<<(N_NODES + 3) / 4, 256, 0, stream>>>(htq, als, ald, rs, csr,
                                                            b2, hf, 1);
    // layer 3 (output into hout = xf)
    gemm_fp16<<<GG, 256, 0, stream>>>(hf, wt3, htq, a3s, a3d, als, ald, HC, N_NODES);
    aggregate_kernel<<<(N_NODES + 3) / 4, 256, 0, stream>>>(htq, als, ald, rs, csr,
                                                            b3, hout, 0);

    pool_kernel<<<G_GRAPHS, 256, 0, stream>>>(hout, gstart, pooled);
    mlp1_kernel<<<G_GRAPHS, 320, 0, stream>>>(pooled, Wm1, bm1, zbuf);
    mlp2_kernel<<<G_GRAPHS, 512, 0, stream>>>(zbuf, Wm2, bm2, out);
}